// Round 3
// baseline (966.302 us; speedup 1.0000x reference)
//
#include <hip/hip_runtime.h>
#include <math.h>

#define BB 1024
#define TT 25
#define LP 10
#define MAXD 11
#define RS 36      // fp32 layer-1 LDS row stride

// MFMA staging buffer geometry (bf16 spikes)
#define XR 42      // padded time rows: reads reach t' = 31+10 = 41
#define XC 264     // column stride (256 + 8 pad)
#define XSZ (XR * XC)

typedef __bf16 bf16x8 __attribute__((ext_vector_type(8)));
typedef float  f32x4  __attribute__((ext_vector_type(4)));

// ---------------------------------------------------------------------------
// Layer-1 dense DCLS kernel (fp32), transposed layout Kt[(i*MAXD+j)*O + o]
// ---------------------------------------------------------------------------
__global__ void gen_kernel(const float* __restrict__ W,
                           const float* __restrict__ P,
                           const float* __restrict__ SIG,
                           float* __restrict__ Kt, int O, int I) {
    int idx = blockIdx.x * blockDim.x + threadIdx.x;
    if (idx >= O * I) return;
    int i = idx % I;
    int o = idx / I;
    float w  = W[idx];
    float pc = P[idx] + (float)(MAXD / 2);
    float s  = fabsf(SIG[idx]) + 0.27f;
    float x[MAXD];
    float sum = 0.f;
#pragma unroll
    for (int j = 0; j < MAXD; ++j) {
        float d = ((float)j - pc) / s;
        x[j] = expf(-0.5f * d * d);
        sum += x[j];
    }
    float denom = sum + 1e-7f;
#pragma unroll
    for (int j = 0; j < MAXD; ++j) {
        Kt[(i * MAXD + j) * O + o] = w * (x[j] / denom);
    }
}

// ---------------------------------------------------------------------------
// Triple-split bf16 DCLS taps: K == Khi + Kmid + Klo EXACTLY (24 mantissa
// bits covered by 3 RNE bf16 splits). Layout [j][Opad][I] each; o>=O rows 0.
// ---------------------------------------------------------------------------
__global__ void gen_trip(const float* __restrict__ W,
                         const float* __restrict__ P,
                         const float* __restrict__ SIG,
                         __bf16* __restrict__ Khi, __bf16* __restrict__ Kmid,
                         __bf16* __restrict__ Klo,
                         int O, int Opad, int I) {
    int idx = blockIdx.x * blockDim.x + threadIdx.x;
    if (idx >= Opad * I) return;
    int i = idx % I;
    int o = idx / I;
    if (o >= O) {
#pragma unroll
        for (int j = 0; j < MAXD; ++j) {
            size_t ofs = ((size_t)(j * Opad + o)) * I + i;
            Khi[ofs] = (__bf16)0.0f;
            Kmid[ofs] = (__bf16)0.0f;
            Klo[ofs] = (__bf16)0.0f;
        }
        return;
    }
    int widx = o * I + i;
    float w  = W[widx];
    float pc = P[widx] + (float)(MAXD / 2);
    float s  = fabsf(SIG[widx]) + 0.27f;
    float x[MAXD];
    float sum = 0.f;
#pragma unroll
    for (int j = 0; j < MAXD; ++j) {
        float d = ((float)j - pc) / s;
        x[j] = expf(-0.5f * d * d);
        sum += x[j];
    }
    float denom = sum + 1e-7f;
#pragma unroll
    for (int j = 0; j < MAXD; ++j) {
        float kv = w * (x[j] / denom);
        __bf16 h = (__bf16)kv;
        float  r1 = kv - (float)h;
        __bf16 m = (__bf16)r1;
        float  r2 = r1 - (float)m;
        __bf16 l = (__bf16)r2;
        size_t ofs = ((size_t)(j * Opad + o)) * I + i;
        Khi[ofs] = h;
        Kmid[ofs] = m;
        Klo[ofs] = l;
    }
}

// ---------------------------------------------------------------------------
// Layer 1 (fp32 vector): DCLS conv + bias + BN + LIF; spikes out as bf16.
// ---------------------------------------------------------------------------
template <int I>
__global__ __launch_bounds__(256)
void conv_bn_lif_kernel(const float* __restrict__ xin,
                        const float* __restrict__ Kt,
                        const float* __restrict__ bias,
                        const float* __restrict__ gamma,
                        const float* __restrict__ beta,
                        const float* __restrict__ mean,
                        const float* __restrict__ var,
                        __bf16* __restrict__ spk_out) {
    __shared__ __align__(16) float xs[I * RS];
    const int b   = blockIdx.x;
    const int tid = threadIdx.x;

    for (int k = tid; k < I * RS; k += 256) xs[k] = 0.f;
    __syncthreads();
    for (int k = tid; k < TT * I; k += 256) {
        int t = k / I;
        int i = k - t * I;
        xs[i * RS + LP + t] = xin[b * TT * I + k];
    }
    __syncthreads();

    const int o = tid;
    float y[TT];
#pragma unroll
    for (int t = 0; t < TT; ++t) y[t] = 0.f;

    for (int i = 0; i < I; ++i) {
        float xr[RS];
        const float4* xp = reinterpret_cast<const float4*>(&xs[i * RS]);
#pragma unroll
        for (int q = 0; q < RS / 4; ++q) {
            float4 v = xp[q];
            xr[4 * q + 0] = v.x; xr[4 * q + 1] = v.y;
            xr[4 * q + 2] = v.z; xr[4 * q + 3] = v.w;
        }
        float kv[MAXD];
        const float* kp = &Kt[i * MAXD * 256 + o];
#pragma unroll
        for (int j = 0; j < MAXD; ++j) kv[j] = kp[j * 256];
#pragma unroll
        for (int j = 0; j < MAXD; ++j) {
            float kj = kv[j];
#pragma unroll
            for (int t = 0; t < TT; ++t) y[t] = fmaf(kj, xr[t + j], y[t]);
        }
    }

    float scale = gamma[o] / sqrtf(var[o] + 1e-5f);
    float ofs   = (bias[o] - mean[o]) * scale + beta[o];

    float memv = 0.f;
#pragma unroll
    for (int t = 0; t < TT; ++t) {
        float a     = y[t] * scale + ofs;
        float reset = (memv > 1.0f) ? 1.0f : 0.f;
        memv        = 0.95f * memv + a - reset;
        spk_out[(b * TT + t) * 256 + o] = (memv > 1.0f) ? (__bf16)1.0f : (__bf16)0.0f;
    }
}

// ---------------------------------------------------------------------------
// Layer 2 (MFMA): conv over spikes with exact triple-split taps + BN + LIF.
// Block = 2 batches, 256 threads = 4 waves. A = taps (m=o), B = spikes (n=t),
// k = input channel. D[m=o][n=t] per 16x16x32 bf16 MFMA.
// ---------------------------------------------------------------------------
__global__ __launch_bounds__(256)
void conv2_mfma(const __bf16* __restrict__ spk1,
                const __bf16* __restrict__ Khi,
                const __bf16* __restrict__ Kmid,
                const __bf16* __restrict__ Klo,
                const float* __restrict__ bias,
                const float* __restrict__ gamma,
                const float* __restrict__ beta,
                const float* __restrict__ mean,
                const float* __restrict__ var,
                __bf16* __restrict__ spk2) {
    __shared__ __align__(16) char smem[55296];   // max(xs 44352, ys 55296)
    __bf16* xs = (__bf16*)smem;                  // [2][XR][XC]
    float*  ys = (float*)smem;                   // [2][256][27]

    const int b0   = blockIdx.x * 2;
    const int tid  = threadIdx.x;
    const int wave = tid >> 6;
    const int lane = tid & 63;
    const int lm   = lane & 15;
    const int quad = lane >> 4;

    // zero the spike staging buffer (2*XSZ bf16 == XSZ u32 words)
    uint32_t* xz = (uint32_t*)smem;
    for (int k = tid; k < XSZ; k += 256) xz[k] = 0u;
    __syncthreads();
#pragma unroll
    for (int bl = 0; bl < 2; ++bl) {
        const __bf16* src = spk1 + (size_t)(b0 + bl) * (TT * 256);
        for (int k = tid; k < TT * 256; k += 256) {
            int t = k >> 8, i = k & 255;
            xs[bl * XSZ + (LP + t) * XC + i] = src[k];
        }
    }
    __syncthreads();

    f32x4 acc[4][4];
#pragma unroll
    for (int p = 0; p < 4; ++p)
#pragma unroll
        for (int nt = 0; nt < 4; ++nt) acc[p][nt] = (f32x4){0.f, 0.f, 0.f, 0.f};

    const int obase0 = wave * 64;   // wave covers o in [obase0, obase0+64)

    for (int j = 0; j < MAXD; ++j) {
        const int browj = lm + j;
        for (int ic = 0; ic < 8; ++ic) {
            const int col = ic * 32 + quad * 8;
            bf16x8 Bf[4];
#pragma unroll
            for (int bl = 0; bl < 2; ++bl)
#pragma unroll
                for (int th = 0; th < 2; ++th)
                    Bf[bl * 2 + th] =
                        *(const bf16x8*)&xs[bl * XSZ + (th * 16 + browj) * XC + col];
#pragma unroll
            for (int p = 0; p < 4; ++p) {
                const size_t kofs =
                    ((size_t)(j * 256 + obase0 + p * 16 + lm)) * 256 + col;
                bf16x8 Ah = *(const bf16x8*)(Khi + kofs);
                bf16x8 Am = *(const bf16x8*)(Kmid + kofs);
                bf16x8 Al = *(const bf16x8*)(Klo + kofs);
#pragma unroll
                for (int nt = 0; nt < 4; ++nt) {
                    acc[p][nt] = __builtin_amdgcn_mfma_f32_16x16x32_bf16(
                        Ah, Bf[nt], acc[p][nt], 0, 0, 0);
                    acc[p][nt] = __builtin_amdgcn_mfma_f32_16x16x32_bf16(
                        Am, Bf[nt], acc[p][nt], 0, 0, 0);
                    acc[p][nt] = __builtin_amdgcn_mfma_f32_16x16x32_bf16(
                        Al, Bf[nt], acc[p][nt], 0, 0, 0);
                }
            }
        }
    }
    __syncthreads();   // xs dead; reuse smem as ys

#pragma unroll
    for (int p = 0; p < 4; ++p)
#pragma unroll
        for (int nt = 0; nt < 4; ++nt) {
            int bl = nt >> 1;
            int t  = (nt & 1) * 16 + lm;
            if (t < TT) {
                int ob = obase0 + p * 16 + quad * 4;
#pragma unroll
                for (int v = 0; v < 4; ++v)
                    ys[(bl * 256 + ob + v) * 27 + t] = acc[p][nt][v];
            }
        }
    __syncthreads();

    // BN + LIF per output channel
    const int o = tid;
    float scale = gamma[o] / sqrtf(var[o] + 1e-5f);
    float ofs   = (bias[o] - mean[o]) * scale + beta[o];
#pragma unroll
    for (int bl = 0; bl < 2; ++bl) {
        float memv = 0.f;
        __bf16* dst = spk2 + (size_t)(b0 + bl) * (TT * 256) + o;
        const float* yrow = &ys[(bl * 256 + o) * 27];
#pragma unroll
        for (int t = 0; t < TT; ++t) {
            float a     = yrow[t] * scale + ofs;
            float reset = (memv > 1.0f) ? 1.0f : 0.f;
            memv        = 0.95f * memv + a - reset;
            dst[t * 256] = (memv > 1.0f) ? (__bf16)1.0f : (__bf16)0.0f;
        }
    }
}

// ---------------------------------------------------------------------------
// Layer 3 (MFMA): O padded 20->32, bias + LIF, writes spk3 ++ mem3 (fp32).
// ---------------------------------------------------------------------------
__global__ __launch_bounds__(256)
void conv3_mfma(const __bf16* __restrict__ spk2,
                const __bf16* __restrict__ K3hi,
                const __bf16* __restrict__ K3mid,
                const __bf16* __restrict__ K3lo,
                const float* __restrict__ b3,
                float* __restrict__ out) {
    __shared__ __align__(16) __bf16 xs[2 * XSZ];
    __shared__ float ys[2 * 32 * 27];

    const int b0   = blockIdx.x * 2;
    const int tid  = threadIdx.x;
    const int wave = tid >> 6;
    const int lane = tid & 63;
    const int lm   = lane & 15;
    const int quad = lane >> 4;

    uint32_t* xz = (uint32_t*)xs;
    for (int k = tid; k < XSZ; k += 256) xz[k] = 0u;
    __syncthreads();
#pragma unroll
    for (int bl = 0; bl < 2; ++bl) {
        const __bf16* src = spk2 + (size_t)(b0 + bl) * (TT * 256);
        for (int k = tid; k < TT * 256; k += 256) {
            int t = k >> 8, i = k & 255;
            xs[bl * XSZ + (LP + t) * XC + i] = src[k];
        }
    }
    __syncthreads();

    f32x4 acc[2];
#pragma unroll
    for (int p = 0; p < 2; ++p) acc[p] = (f32x4){0.f, 0.f, 0.f, 0.f};

    const int bl = wave >> 1;   // batch handled by this wave
    const int th = wave & 1;    // t half

    for (int j = 0; j < MAXD; ++j) {
        const int brow = th * 16 + lm + j;
        for (int ic = 0; ic < 8; ++ic) {
            const int col = ic * 32 + quad * 8;
            bf16x8 Bf = *(const bf16x8*)&xs[bl * XSZ + brow * XC + col];
#pragma unroll
            for (int p = 0; p < 2; ++p) {
                const size_t kofs = ((size_t)(j * 32 + p * 16 + lm)) * 256 + col;
                bf16x8 Ah = *(const bf16x8*)(K3hi + kofs);
                bf16x8 Am = *(const bf16x8*)(K3mid + kofs);
                bf16x8 Al = *(const bf16x8*)(K3lo + kofs);
                acc[p] = __builtin_amdgcn_mfma_f32_16x16x32_bf16(Ah, Bf, acc[p], 0, 0, 0);
                acc[p] = __builtin_amdgcn_mfma_f32_16x16x32_bf16(Am, Bf, acc[p], 0, 0, 0);
                acc[p] = __builtin_amdgcn_mfma_f32_16x16x32_bf16(Al, Bf, acc[p], 0, 0, 0);
            }
        }
    }

    {
        int t = th * 16 + lm;
        if (t < TT) {
#pragma unroll
            for (int p = 0; p < 2; ++p)
#pragma unroll
                for (int v = 0; v < 4; ++v)
                    ys[(bl * 32 + p * 16 + quad * 4 + v) * 27 + t] = acc[p][v];
        }
    }
    __syncthreads();

    if (tid < 40) {
        const int bl2 = tid / 20;
        const int o   = tid % 20;
        float memv = 0.f;
        float bo   = b3[o];
        const float* yrow = &ys[(bl2 * 32 + o) * 27];
#pragma unroll
        for (int t = 0; t < TT; ++t) {
            float a     = yrow[t] + bo;
            float reset = (memv > 1.0f) ? 1.0f : 0.f;
            memv        = 0.95f * memv + a - reset;
            float spk   = (memv > 1.0f) ? 1.0f : 0.f;
            out[(t * BB + (b0 + bl2)) * 20 + o]          = spk;
            out[TT * BB * 20 + (t * BB + (b0 + bl2)) * 20 + o] = memv;
        }
    }
}

// ---------------------------------------------------------------------------
extern "C" void kernel_launch(void* const* d_in, const int* in_sizes, int n_in,
                              void* d_out, int out_size, void* d_ws, size_t ws_size,
                              hipStream_t stream) {
    const float* data = (const float*)d_in[0];
    const float* W1   = (const float*)d_in[1];
    const float* b1   = (const float*)d_in[2];
    const float* P1   = (const float*)d_in[3];
    const float* SIG1 = (const float*)d_in[4];
    const float* g1   = (const float*)d_in[5];
    const float* be1  = (const float*)d_in[6];
    const float* m1   = (const float*)d_in[7];
    const float* v1   = (const float*)d_in[8];
    const float* W2   = (const float*)d_in[9];
    const float* b2   = (const float*)d_in[10];
    const float* P2   = (const float*)d_in[11];
    const float* SIG2 = (const float*)d_in[12];
    const float* g2   = (const float*)d_in[13];
    const float* be2  = (const float*)d_in[14];
    const float* m2   = (const float*)d_in[15];
    const float* v2   = (const float*)d_in[16];
    const float* W3   = (const float*)d_in[17];
    const float* b3   = (const float*)d_in[18];
    const float* P3   = (const float*)d_in[19];
    const float* SIG3 = (const float*)d_in[20];
    float* out = (float*)d_out;

    // workspace layout (byte offsets, all 16B-aligned)
    char* ws = (char*)d_ws;
    float*  K1t  = (float*)ws;                         // 394240 f32 = 1576960 B
    __bf16* spk1 = (__bf16*)(ws + 1576960);            // 6553600 bf16 = 13107200 B
    __bf16* spk2 = (__bf16*)(ws + 1576960 + 13107200); // 13107200 B
    char* p = ws + 1576960 + 2 * 13107200;
    __bf16* K2hi  = (__bf16*)p;               p += 1441792;  // 11*256*256 bf16
    __bf16* K2mid = (__bf16*)p;               p += 1441792;
    __bf16* K2lo  = (__bf16*)p;               p += 1441792;
    __bf16* K3hi  = (__bf16*)p;               p += 180224;   // 11*32*256 bf16
    __bf16* K3mid = (__bf16*)p;               p += 180224;
    __bf16* K3lo  = (__bf16*)p;

    gen_kernel<<<(256 * 140 + 255) / 256, 256, 0, stream>>>(W1, P1, SIG1, K1t, 256, 140);
    gen_trip<<<(256 * 256 + 255) / 256, 256, 0, stream>>>(W2, P2, SIG2, K2hi, K2mid, K2lo, 256, 256, 256);
    gen_trip<<<(32 * 256 + 255) / 256, 256, 0, stream>>>(W3, P3, SIG3, K3hi, K3mid, K3lo, 20, 32, 256);

    conv_bn_lif_kernel<140><<<BB, 256, 0, stream>>>(data, K1t, b1, g1, be1, m1, v1, spk1);
    conv2_mfma<<<BB / 2, 256, 0, stream>>>(spk1, K2hi, K2mid, K2lo, b2, g2, be2, m2, v2, spk2);
    conv3_mfma<<<BB / 2, 256, 0, stream>>>(spk2, K3hi, K3mid, K3lo, b3, out);
}

// Round 4
// 709.992 us; speedup vs baseline: 1.3610x; 1.3610x over previous
//
#include <hip/hip_runtime.h>
#include <math.h>

#define BB 1024
#define TT 25
#define LP 10
#define MAXD 11
#define RS 36      // fp32 layer-1 LDS row stride

// conv2 compact spike staging: rows 0..24 = spikes, row 25 = zeros
#define XR2 26
#define XC 264     // column stride (256 + 8 pad), 16B-aligned rows
#define XSZ2 (XR2 * XC)

// conv3 staging (round-3 layout, unchanged)
#define XR 42
#define XSZ (XR * XC)

typedef __bf16 bf16x8 __attribute__((ext_vector_type(8)));
typedef float  f32x4  __attribute__((ext_vector_type(4)));

// ---------------------------------------------------------------------------
// Layer-1 dense DCLS kernel (fp32), transposed layout Kt[(i*MAXD+j)*O + o]
// ---------------------------------------------------------------------------
__global__ void gen_kernel(const float* __restrict__ W,
                           const float* __restrict__ P,
                           const float* __restrict__ SIG,
                           float* __restrict__ Kt, int O, int I) {
    int idx = blockIdx.x * blockDim.x + threadIdx.x;
    if (idx >= O * I) return;
    int i = idx % I;
    int o = idx / I;
    float w  = W[idx];
    float pc = P[idx] + (float)(MAXD / 2);
    float s  = fabsf(SIG[idx]) + 0.27f;
    float x[MAXD];
    float sum = 0.f;
#pragma unroll
    for (int j = 0; j < MAXD; ++j) {
        float d = ((float)j - pc) / s;
        x[j] = expf(-0.5f * d * d);
        sum += x[j];
    }
    float denom = sum + 1e-7f;
#pragma unroll
    for (int j = 0; j < MAXD; ++j) {
        Kt[(i * MAXD + j) * O + o] = w * (x[j] / denom);
    }
}

// ---------------------------------------------------------------------------
// Triple-split bf16 DCLS taps: K == Khi + Kmid + Klo EXACTLY (24 mantissa
// bits covered by 3 RNE bf16 splits). Layout [j][Opad][I] each; o>=O rows 0.
// ---------------------------------------------------------------------------
__global__ void gen_trip(const float* __restrict__ W,
                         const float* __restrict__ P,
                         const float* __restrict__ SIG,
                         __bf16* __restrict__ Khi, __bf16* __restrict__ Kmid,
                         __bf16* __restrict__ Klo,
                         int O, int Opad, int I) {
    int idx = blockIdx.x * blockDim.x + threadIdx.x;
    if (idx >= Opad * I) return;
    int i = idx % I;
    int o = idx / I;
    if (o >= O) {
#pragma unroll
        for (int j = 0; j < MAXD; ++j) {
            size_t ofs = ((size_t)(j * Opad + o)) * I + i;
            Khi[ofs] = (__bf16)0.0f;
            Kmid[ofs] = (__bf16)0.0f;
            Klo[ofs] = (__bf16)0.0f;
        }
        return;
    }
    int widx = o * I + i;
    float w  = W[widx];
    float pc = P[widx] + (float)(MAXD / 2);
    float s  = fabsf(SIG[widx]) + 0.27f;
    float x[MAXD];
    float sum = 0.f;
#pragma unroll
    for (int j = 0; j < MAXD; ++j) {
        float d = ((float)j - pc) / s;
        x[j] = expf(-0.5f * d * d);
        sum += x[j];
    }
    float denom = sum + 1e-7f;
#pragma unroll
    for (int j = 0; j < MAXD; ++j) {
        float kv = w * (x[j] / denom);
        __bf16 h = (__bf16)kv;
        float  r1 = kv - (float)h;
        __bf16 m = (__bf16)r1;
        float  r2 = r1 - (float)m;
        __bf16 l = (__bf16)r2;
        size_t ofs = ((size_t)(j * Opad + o)) * I + i;
        Khi[ofs] = h;
        Kmid[ofs] = m;
        Klo[ofs] = l;
    }
}

// ---------------------------------------------------------------------------
// Layer 1 (fp32 vector): DCLS conv + bias + BN + LIF; spikes out as bf16.
// launch_bounds(256,2): 256-VGPR budget so xr[36]+y[25] stay in registers.
// ---------------------------------------------------------------------------
template <int I>
__global__ __launch_bounds__(256, 2)
void conv_bn_lif_kernel(const float* __restrict__ xin,
                        const float* __restrict__ Kt,
                        const float* __restrict__ bias,
                        const float* __restrict__ gamma,
                        const float* __restrict__ beta,
                        const float* __restrict__ mean,
                        const float* __restrict__ var,
                        __bf16* __restrict__ spk_out) {
    __shared__ __align__(16) float xs[I * RS];
    const int b   = blockIdx.x;
    const int tid = threadIdx.x;

    for (int k = tid; k < I * RS; k += 256) xs[k] = 0.f;
    __syncthreads();
    for (int k = tid; k < TT * I; k += 256) {
        int t = k / I;
        int i = k - t * I;
        xs[i * RS + LP + t] = xin[b * TT * I + k];
    }
    __syncthreads();

    const int o = tid;
    float y[TT];
#pragma unroll
    for (int t = 0; t < TT; ++t) y[t] = 0.f;

    for (int i = 0; i < I; ++i) {
        float xr[RS];
        const float4* xp = reinterpret_cast<const float4*>(&xs[i * RS]);
#pragma unroll
        for (int q = 0; q < RS / 4; ++q) {
            float4 v = xp[q];
            xr[4 * q + 0] = v.x; xr[4 * q + 1] = v.y;
            xr[4 * q + 2] = v.z; xr[4 * q + 3] = v.w;
        }
        float kv[MAXD];
        const float* kp = &Kt[i * MAXD * 256 + o];
#pragma unroll
        for (int j = 0; j < MAXD; ++j) kv[j] = kp[j * 256];
#pragma unroll
        for (int j = 0; j < MAXD; ++j) {
            float kj = kv[j];
#pragma unroll
            for (int t = 0; t < TT; ++t) y[t] = fmaf(kj, xr[t + j], y[t]);
        }
    }

    float scale = gamma[o] / sqrtf(var[o] + 1e-5f);
    float ofs   = (bias[o] - mean[o]) * scale + beta[o];

    // raw bf16 bit patterns: 1.0f = 0x3F80, 0.0f = 0x0000 (avoids cvt path)
    unsigned short* dst = (unsigned short*)spk_out;
    float memv = 0.f;
#pragma unroll
    for (int t = 0; t < TT; ++t) {
        float a     = y[t] * scale + ofs;
        float reset = (memv > 1.0f) ? 1.0f : 0.f;
        memv        = 0.95f * memv + a - reset;
        dst[(b * TT + t) * 256 + o] = (memv > 1.0f) ? 0x3F80 : 0;
    }
}

// ---------------------------------------------------------------------------
// Layer 2 (MFMA, high-occupancy): 512 threads = 8 waves; wave w owns o-range
// [w*32, w*32+32). 2 batches/block, compact 26-row clamped spike staging.
// A = triple-split taps (m=o), B = spikes (n=t), k = input channel.
// ---------------------------------------------------------------------------
__global__ __launch_bounds__(512, 4)
void conv2_mfma(const __bf16* __restrict__ spk1,
                const __bf16* __restrict__ Khi,
                const __bf16* __restrict__ Kmid,
                const __bf16* __restrict__ Klo,
                const float* __restrict__ bias,
                const float* __restrict__ gamma,
                const float* __restrict__ beta,
                const float* __restrict__ mean,
                const float* __restrict__ var,
                __bf16* __restrict__ spk2) {
    __shared__ __align__(16) char smem[27648];   // xs 27456 B / ys 27648 B
    __bf16* xs = (__bf16*)smem;                  // [2][XR2][XC]
    float*  ys = (float*)smem;                   // [256][27] (per-batch pass)

    const int b0   = blockIdx.x * 2;
    const int tid  = threadIdx.x;
    const int w    = tid >> 6;     // wave 0..7
    const int lane = tid & 63;
    const int lm   = lane & 15;
    const int quad = lane >> 4;

    // zero staging (incl. zero-row 25), then fill rows 0..24
    {
        uint32_t* xz = (uint32_t*)smem;
        for (int k = tid; k < XSZ2; k += 512) xz[k] = 0u;   // 2*XSZ2 bf16
    }
    __syncthreads();
#pragma unroll
    for (int bl = 0; bl < 2; ++bl) {
        const __bf16* src = spk1 + (size_t)(b0 + bl) * (TT * 256);
        for (int k = tid; k < TT * 256; k += 512) {
            int t = k >> 8, i = k & 255;
            xs[bl * XSZ2 + t * XC + i] = src[k];
        }
    }
    __syncthreads();

    f32x4 acc[2][4];   // [p][bl*2+th]
#pragma unroll
    for (int p = 0; p < 2; ++p)
#pragma unroll
        for (int nt = 0; nt < 4; ++nt) acc[p][nt] = (f32x4){0.f, 0.f, 0.f, 0.f};

    for (int j = 0; j < MAXD; ++j) {
        // clamped spike row per t-half: r = t' + j - 10, else zero row 25
        int r0 = lm + j - 10;          r0 = ((unsigned)r0 < 25u) ? r0 : 25;
        int r1 = 16 + lm + j - 10;     r1 = ((unsigned)r1 < 25u) ? r1 : 25;
        for (int ic = 0; ic < 8; ++ic) {
            const int col = ic * 32 + quad * 8;
            bf16x8 Bf[4];
#pragma unroll
            for (int bl = 0; bl < 2; ++bl) {
                Bf[bl * 2 + 0] = *(const bf16x8*)&xs[bl * XSZ2 + r0 * XC + col];
                Bf[bl * 2 + 1] = *(const bf16x8*)&xs[bl * XSZ2 + r1 * XC + col];
            }
#pragma unroll
            for (int p = 0; p < 2; ++p) {
                const size_t kofs =
                    ((size_t)(j * 256 + w * 32 + p * 16 + lm)) * 256 + col;
                bf16x8 Ah = *(const bf16x8*)(Khi + kofs);
                bf16x8 Am = *(const bf16x8*)(Kmid + kofs);
                bf16x8 Al = *(const bf16x8*)(Klo + kofs);
#pragma unroll
                for (int nt = 0; nt < 4; ++nt) {
                    acc[p][nt] = __builtin_amdgcn_mfma_f32_16x16x32_bf16(
                        Ah, Bf[nt], acc[p][nt], 0, 0, 0);
                    acc[p][nt] = __builtin_amdgcn_mfma_f32_16x16x32_bf16(
                        Am, Bf[nt], acc[p][nt], 0, 0, 0);
                    acc[p][nt] = __builtin_amdgcn_mfma_f32_16x16x32_bf16(
                        Al, Bf[nt], acc[p][nt], 0, 0, 0);
                }
            }
        }
    }

    // epilogue: one batch at a time through LDS (smem reused as ys)
#pragma unroll
    for (int bl = 0; bl < 2; ++bl) {
        __syncthreads();
#pragma unroll
        for (int p = 0; p < 2; ++p)
#pragma unroll
            for (int th = 0; th < 2; ++th) {
                int t = th * 16 + lm;
                if (t < TT) {
                    int ob = w * 32 + p * 16 + quad * 4;
#pragma unroll
                    for (int v = 0; v < 4; ++v)
                        ys[(ob + v) * 27 + t] = acc[p][bl * 2 + th][v];
                }
            }
        __syncthreads();
        if (tid < 256) {
            const int o = tid;
            float scale = gamma[o] / sqrtf(var[o] + 1e-5f);
            float ofs   = (bias[o] - mean[o]) * scale + beta[o];
            unsigned short* dst =
                (unsigned short*)spk2 + (size_t)(b0 + bl) * (TT * 256) + o;
            const float* yrow = &ys[o * 27];
            float memv = 0.f;
#pragma unroll
            for (int t = 0; t < TT; ++t) {
                float a     = yrow[t] * scale + ofs;
                float reset = (memv > 1.0f) ? 1.0f : 0.f;
                memv        = 0.95f * memv + a - reset;
                dst[t * 256] = (memv > 1.0f) ? 0x3F80 : 0;
            }
        }
    }
}

// ---------------------------------------------------------------------------
// Layer 3 (MFMA): O padded 20->32, bias + LIF, writes spk3 ++ mem3 (fp32).
// ---------------------------------------------------------------------------
__global__ __launch_bounds__(256)
void conv3_mfma(const __bf16* __restrict__ spk2,
                const __bf16* __restrict__ K3hi,
                const __bf16* __restrict__ K3mid,
                const __bf16* __restrict__ K3lo,
                const float* __restrict__ b3,
                float* __restrict__ out) {
    __shared__ __align__(16) __bf16 xs[2 * XSZ];
    __shared__ float ys[2 * 32 * 27];

    const int b0   = blockIdx.x * 2;
    const int tid  = threadIdx.x;
    const int wave = tid >> 6;
    const int lane = tid & 63;
    const int lm   = lane & 15;
    const int quad = lane >> 4;

    uint32_t* xz = (uint32_t*)xs;
    for (int k = tid; k < XSZ; k += 256) xz[k] = 0u;
    __syncthreads();
#pragma unroll
    for (int bl = 0; bl < 2; ++bl) {
        const __bf16* src = spk2 + (size_t)(b0 + bl) * (TT * 256);
        for (int k = tid; k < TT * 256; k += 256) {
            int t = k >> 8, i = k & 255;
            xs[bl * XSZ + (LP + t) * XC + i] = src[k];
        }
    }
    __syncthreads();

    f32x4 acc[2];
#pragma unroll
    for (int p = 0; p < 2; ++p) acc[p] = (f32x4){0.f, 0.f, 0.f, 0.f};

    const int bl = wave >> 1;   // batch handled by this wave
    const int th = wave & 1;    // t half

    for (int j = 0; j < MAXD; ++j) {
        const int brow = th * 16 + lm + j;
        for (int ic = 0; ic < 8; ++ic) {
            const int col = ic * 32 + quad * 8;
            bf16x8 Bf = *(const bf16x8*)&xs[bl * XSZ + brow * XC + col];
#pragma unroll
            for (int p = 0; p < 2; ++p) {
                const size_t kofs = ((size_t)(j * 32 + p * 16 + lm)) * 256 + col;
                bf16x8 Ah = *(const bf16x8*)(K3hi + kofs);
                bf16x8 Am = *(const bf16x8*)(K3mid + kofs);
                bf16x8 Al = *(const bf16x8*)(K3lo + kofs);
                acc[p] = __builtin_amdgcn_mfma_f32_16x16x32_bf16(Ah, Bf, acc[p], 0, 0, 0);
                acc[p] = __builtin_amdgcn_mfma_f32_16x16x32_bf16(Am, Bf, acc[p], 0, 0, 0);
                acc[p] = __builtin_amdgcn_mfma_f32_16x16x32_bf16(Al, Bf, acc[p], 0, 0, 0);
            }
        }
    }

    {
        int t = th * 16 + lm;
        if (t < TT) {
#pragma unroll
            for (int p = 0; p < 2; ++p)
#pragma unroll
                for (int v = 0; v < 4; ++v)
                    ys[(bl * 32 + p * 16 + quad * 4 + v) * 27 + t] = acc[p][v];
        }
    }
    __syncthreads();

    if (tid < 40) {
        const int bl2 = tid / 20;
        const int o   = tid % 20;
        float memv = 0.f;
        float bo   = b3[o];
        const float* yrow = &ys[(bl2 * 32 + o) * 27];
#pragma unroll
        for (int t = 0; t < TT; ++t) {
            float a     = yrow[t] + bo;
            float reset = (memv > 1.0f) ? 1.0f : 0.f;
            memv        = 0.95f * memv + a - reset;
            float spk   = (memv > 1.0f) ? 1.0f : 0.f;
            out[(t * BB + (b0 + bl2)) * 20 + o]          = spk;
            out[TT * BB * 20 + (t * BB + (b0 + bl2)) * 20 + o] = memv;
        }
    }
}

// ---------------------------------------------------------------------------
extern "C" void kernel_launch(void* const* d_in, const int* in_sizes, int n_in,
                              void* d_out, int out_size, void* d_ws, size_t ws_size,
                              hipStream_t stream) {
    const float* data = (const float*)d_in[0];
    const float* W1   = (const float*)d_in[1];
    const float* b1   = (const float*)d_in[2];
    const float* P1   = (const float*)d_in[3];
    const float* SIG1 = (const float*)d_in[4];
    const float* g1   = (const float*)d_in[5];
    const float* be1  = (const float*)d_in[6];
    const float* m1   = (const float*)d_in[7];
    const float* v1   = (const float*)d_in[8];
    const float* W2   = (const float*)d_in[9];
    const float* b2   = (const float*)d_in[10];
    const float* P2   = (const float*)d_in[11];
    const float* SIG2 = (const float*)d_in[12];
    const float* g2   = (const float*)d_in[13];
    const float* be2  = (const float*)d_in[14];
    const float* m2   = (const float*)d_in[15];
    const float* v2   = (const float*)d_in[16];
    const float* W3   = (const float*)d_in[17];
    const float* b3   = (const float*)d_in[18];
    const float* P3   = (const float*)d_in[19];
    const float* SIG3 = (const float*)d_in[20];
    float* out = (float*)d_out;

    // workspace layout (byte offsets, all 16B-aligned)
    char* ws = (char*)d_ws;
    float*  K1t  = (float*)ws;                         // 394240 f32 = 1576960 B
    __bf16* spk1 = (__bf16*)(ws + 1576960);            // 6553600 bf16 = 13107200 B
    __bf16* spk2 = (__bf16*)(ws + 1576960 + 13107200); // 13107200 B
    char* p = ws + 1576960 + 2 * 13107200;
    __bf16* K2hi  = (__bf16*)p;               p += 1441792;  // 11*256*256 bf16
    __bf16* K2mid = (__bf16*)p;               p += 1441792;
    __bf16* K2lo  = (__bf16*)p;               p += 1441792;
    __bf16* K3hi  = (__bf16*)p;               p += 180224;   // 11*32*256 bf16
    __bf16* K3mid = (__bf16*)p;               p += 180224;
    __bf16* K3lo  = (__bf16*)p;

    gen_kernel<<<(256 * 140 + 255) / 256, 256, 0, stream>>>(W1, P1, SIG1, K1t, 256, 140);
    gen_trip<<<(256 * 256 + 255) / 256, 256, 0, stream>>>(W2, P2, SIG2, K2hi, K2mid, K2lo, 256, 256, 256);
    gen_trip<<<(32 * 256 + 255) / 256, 256, 0, stream>>>(W3, P3, SIG3, K3hi, K3mid, K3lo, 20, 32, 256);

    conv_bn_lif_kernel<140><<<BB, 256, 0, stream>>>(data, K1t, b1, g1, be1, m1, v1, spk1);
    conv2_mfma<<<BB / 2, 512, 0, stream>>>(spk1, K2hi, K2mid, K2lo, b2, g2, be2, m2, v2, spk2);
    conv3_mfma<<<BB / 2, 256, 0, stream>>>(spk2, K3hi, K3mid, K3lo, b3, out);
}

// Round 5
// 585.397 us; speedup vs baseline: 1.6507x; 1.2128x over previous
//
#include <hip/hip_runtime.h>
#include <math.h>

#define BB 1024
#define TT 25
#define LP 10
#define MAXD 11

// conv2/conv3 spike staging: rows 0..24 = spikes, row 25 = zeros
#define XR2 26
#define XC 264            // 256 ch + 8 pad, 16B-aligned rows
#define XSZ2 (XR2 * XC)

// conv1 staging: 160 padded channels + 8 pad
#define IC1 140
#define ICP1 160
#define XC1 168
#define XSZ1 (XR2 * XC1)      // per batch, per split: 26*168
#define SS1 (2 * XSZ1)        // per-split stride (2 batches)

typedef __bf16 bf16x8 __attribute__((ext_vector_type(8)));
typedef float  f32x4  __attribute__((ext_vector_type(4)));

// ---------------------------------------------------------------------------
// Triple-split bf16 DCLS taps: K == Khi + Kmid + Klo EXACTLY (Dekker splits:
// each residual subtraction is exact; 3rd residual has <=8 significant bits).
// Layout [j][Opad][Ipad]; rows o>=O and cols i>=I are zero.
// ---------------------------------------------------------------------------
__global__ void gen_trip(const float* __restrict__ W,
                         const float* __restrict__ P,
                         const float* __restrict__ SIG,
                         __bf16* __restrict__ Khi, __bf16* __restrict__ Kmid,
                         __bf16* __restrict__ Klo,
                         int O, int Opad, int I, int Ipad) {
    int idx = blockIdx.x * blockDim.x + threadIdx.x;
    if (idx >= Opad * Ipad) return;
    int i = idx % Ipad;
    int o = idx / Ipad;
    if (o >= O || i >= I) {
#pragma unroll
        for (int j = 0; j < MAXD; ++j) {
            size_t ofs = ((size_t)(j * Opad + o)) * Ipad + i;
            Khi[ofs] = (__bf16)0.0f;
            Kmid[ofs] = (__bf16)0.0f;
            Klo[ofs] = (__bf16)0.0f;
        }
        return;
    }
    int widx = o * I + i;
    float w  = W[widx];
    float pc = P[widx] + (float)(MAXD / 2);
    float s  = fabsf(SIG[widx]) + 0.27f;
    float x[MAXD];
    float sum = 0.f;
#pragma unroll
    for (int j = 0; j < MAXD; ++j) {
        float d = ((float)j - pc) / s;
        x[j] = expf(-0.5f * d * d);
        sum += x[j];
    }
    float denom = sum + 1e-7f;
#pragma unroll
    for (int j = 0; j < MAXD; ++j) {
        float kv = w * (x[j] / denom);
        __bf16 h = (__bf16)kv;
        float  r1 = kv - (float)h;
        __bf16 m = (__bf16)r1;
        float  r2 = r1 - (float)m;
        __bf16 l = (__bf16)r2;
        size_t ofs = ((size_t)(j * Opad + o)) * Ipad + i;
        Khi[ofs] = h;
        Kmid[ofs] = m;
        Klo[ofs] = l;
    }
}

// ---------------------------------------------------------------------------
// Layer 1 (MFMA, exact split-split): fp32 input x is split 3-way into bf16
// LDS planes at staging; taps are 3-way split. 6 product-term MFMAs cover all
// cross terms >= 2^-18 rel (dropped terms below fp32 FMA rounding).
// 512 threads = 8 waves; wave w owns o-range [w*32, w*32+32). 2 batches/blk.
// ---------------------------------------------------------------------------
__global__ __launch_bounds__(512, 4)
void conv1_mfma(const float* __restrict__ xin,     // (B, T, 140)
                const __bf16* __restrict__ Khi,    // [j][256][160]
                const __bf16* __restrict__ Kmid,
                const __bf16* __restrict__ Klo,
                const float* __restrict__ bias,
                const float* __restrict__ gamma,
                const float* __restrict__ beta,
                const float* __restrict__ mean,
                const float* __restrict__ var,
                __bf16* __restrict__ spk1) {
    __shared__ __align__(16) char smem[3 * SS1 * 2];   // 52416 B; ys needs 27648
    __bf16* xs = (__bf16*)smem;                        // [split][bl][26][168]
    float*  ys = (float*)smem;                         // [256][27] per-batch

    const int b0   = blockIdx.x * 2;
    const int tid  = threadIdx.x;
    const int w    = tid >> 6;
    const int lane = tid & 63;
    const int lm   = lane & 15;
    const int quad = lane >> 4;

    // zero all three split planes (incl. zero-row 25 and pad cols)
    {
        uint32_t* xz = (uint32_t*)smem;
        for (int k = tid; k < 3 * SS1 / 2; k += 512) xz[k] = 0u;
    }
    __syncthreads();
    // fill + split: xs[s][bl][t][i]
#pragma unroll
    for (int bl = 0; bl < 2; ++bl) {
        const float* src = xin + (size_t)(b0 + bl) * (TT * IC1);
        for (int k = tid; k < TT * IC1; k += 512) {
            int t = k / IC1;
            int i = k - t * IC1;
            float x  = src[k];
            __bf16 h = (__bf16)x;
            float r1 = x - (float)h;
            __bf16 m = (__bf16)r1;
            float r2 = r1 - (float)m;
            __bf16 l = (__bf16)r2;
            int ofs = bl * XSZ1 + t * XC1 + i;
            xs[0 * SS1 + ofs] = h;
            xs[1 * SS1 + ofs] = m;
            xs[2 * SS1 + ofs] = l;
        }
    }
    __syncthreads();

    f32x4 acc[2][4];   // [p][bl*2+th]
#pragma unroll
    for (int p = 0; p < 2; ++p)
#pragma unroll
        for (int nt = 0; nt < 4; ++nt) acc[p][nt] = (f32x4){0.f, 0.f, 0.f, 0.f};

    for (int j = 0; j < MAXD; ++j) {
        int r0 = lm + j - 10;          r0 = ((unsigned)r0 < 25u) ? r0 : 25;
        int r1 = 16 + lm + j - 10;     r1 = ((unsigned)r1 < 25u) ? r1 : 25;
        for (int ic = 0; ic < 5; ++ic) {
            const int col = ic * 32 + quad * 8;
            bf16x8 Ah[2], Am[2], Al[2];
#pragma unroll
            for (int p = 0; p < 2; ++p) {
                const size_t kofs =
                    ((size_t)(j * 256 + w * 32 + p * 16 + lm)) * ICP1 + col;
                Ah[p] = *(const bf16x8*)(Khi + kofs);
                Am[p] = *(const bf16x8*)(Kmid + kofs);
                Al[p] = *(const bf16x8*)(Klo + kofs);
            }
#pragma unroll
            for (int bl = 0; bl < 2; ++bl) {
#pragma unroll
                for (int th = 0; th < 2; ++th) {
                    const int row = th ? r1 : r0;
                    const int ofs = bl * XSZ1 + row * XC1 + col;
                    bf16x8 Bh = *(const bf16x8*)&xs[0 * SS1 + ofs];
                    bf16x8 Bm = *(const bf16x8*)&xs[1 * SS1 + ofs];
                    bf16x8 Bl = *(const bf16x8*)&xs[2 * SS1 + ofs];
                    const int nt = bl * 2 + th;
#pragma unroll
                    for (int p = 0; p < 2; ++p) {
                        acc[p][nt] = __builtin_amdgcn_mfma_f32_16x16x32_bf16(
                            Ah[p], Bh, acc[p][nt], 0, 0, 0);
                        acc[p][nt] = __builtin_amdgcn_mfma_f32_16x16x32_bf16(
                            Ah[p], Bm, acc[p][nt], 0, 0, 0);
                        acc[p][nt] = __builtin_amdgcn_mfma_f32_16x16x32_bf16(
                            Am[p], Bh, acc[p][nt], 0, 0, 0);
                        acc[p][nt] = __builtin_amdgcn_mfma_f32_16x16x32_bf16(
                            Ah[p], Bl, acc[p][nt], 0, 0, 0);
                        acc[p][nt] = __builtin_amdgcn_mfma_f32_16x16x32_bf16(
                            Am[p], Bm, acc[p][nt], 0, 0, 0);
                        acc[p][nt] = __builtin_amdgcn_mfma_f32_16x16x32_bf16(
                            Al[p], Bh, acc[p][nt], 0, 0, 0);
                    }
                }
            }
        }
    }

    // epilogue: per batch through LDS, then BN + LIF
#pragma unroll
    for (int bl = 0; bl < 2; ++bl) {
        __syncthreads();
#pragma unroll
        for (int p = 0; p < 2; ++p)
#pragma unroll
            for (int th = 0; th < 2; ++th) {
                int t = th * 16 + lm;
                if (t < TT) {
                    int ob = w * 32 + p * 16 + quad * 4;
#pragma unroll
                    for (int v = 0; v < 4; ++v)
                        ys[(ob + v) * 27 + t] = acc[p][bl * 2 + th][v];
                }
            }
        __syncthreads();
        if (tid < 256) {
            const int o = tid;
            float scale = gamma[o] / sqrtf(var[o] + 1e-5f);
            float ofs   = (bias[o] - mean[o]) * scale + beta[o];
            unsigned short* dst =
                (unsigned short*)spk1 + (size_t)(b0 + bl) * (TT * 256) + o;
            const float* yrow = &ys[o * 27];
            float memv = 0.f;
#pragma unroll
            for (int t = 0; t < TT; ++t) {
                float a     = yrow[t] * scale + ofs;
                float reset = (memv > 1.0f) ? 1.0f : 0.f;
                memv        = 0.95f * memv + a - reset;
                dst[t * 256] = (memv > 1.0f) ? 0x3F80 : 0;
            }
        }
    }
}

// ---------------------------------------------------------------------------
// Layer 2 (MFMA): unchanged from round 4 (passed; conv2 left top-5).
// ---------------------------------------------------------------------------
__global__ __launch_bounds__(512, 4)
void conv2_mfma(const __bf16* __restrict__ spk1,
                const __bf16* __restrict__ Khi,
                const __bf16* __restrict__ Kmid,
                const __bf16* __restrict__ Klo,
                const float* __restrict__ bias,
                const float* __restrict__ gamma,
                const float* __restrict__ beta,
                const float* __restrict__ mean,
                const float* __restrict__ var,
                __bf16* __restrict__ spk2) {
    __shared__ __align__(16) char smem[27648];   // xs 27456 B / ys 27648 B
    __bf16* xs = (__bf16*)smem;                  // [2][XR2][XC]
    float*  ys = (float*)smem;                   // [256][27] (per-batch pass)

    const int b0   = blockIdx.x * 2;
    const int tid  = threadIdx.x;
    const int w    = tid >> 6;
    const int lane = tid & 63;
    const int lm   = lane & 15;
    const int quad = lane >> 4;

    {
        uint32_t* xz = (uint32_t*)smem;
        for (int k = tid; k < XSZ2; k += 512) xz[k] = 0u;
    }
    __syncthreads();
#pragma unroll
    for (int bl = 0; bl < 2; ++bl) {
        const __bf16* src = spk1 + (size_t)(b0 + bl) * (TT * 256);
        for (int k = tid; k < TT * 256; k += 512) {
            int t = k >> 8, i = k & 255;
            xs[bl * XSZ2 + t * XC + i] = src[k];
        }
    }
    __syncthreads();

    f32x4 acc[2][4];
#pragma unroll
    for (int p = 0; p < 2; ++p)
#pragma unroll
        for (int nt = 0; nt < 4; ++nt) acc[p][nt] = (f32x4){0.f, 0.f, 0.f, 0.f};

    for (int j = 0; j < MAXD; ++j) {
        int r0 = lm + j - 10;          r0 = ((unsigned)r0 < 25u) ? r0 : 25;
        int r1 = 16 + lm + j - 10;     r1 = ((unsigned)r1 < 25u) ? r1 : 25;
        for (int ic = 0; ic < 8; ++ic) {
            const int col = ic * 32 + quad * 8;
            bf16x8 Bf[4];
#pragma unroll
            for (int bl = 0; bl < 2; ++bl) {
                Bf[bl * 2 + 0] = *(const bf16x8*)&xs[bl * XSZ2 + r0 * XC + col];
                Bf[bl * 2 + 1] = *(const bf16x8*)&xs[bl * XSZ2 + r1 * XC + col];
            }
#pragma unroll
            for (int p = 0; p < 2; ++p) {
                const size_t kofs =
                    ((size_t)(j * 256 + w * 32 + p * 16 + lm)) * 256 + col;
                bf16x8 Ah = *(const bf16x8*)(Khi + kofs);
                bf16x8 Am = *(const bf16x8*)(Kmid + kofs);
                bf16x8 Al = *(const bf16x8*)(Klo + kofs);
#pragma unroll
                for (int nt = 0; nt < 4; ++nt) {
                    acc[p][nt] = __builtin_amdgcn_mfma_f32_16x16x32_bf16(
                        Ah, Bf[nt], acc[p][nt], 0, 0, 0);
                    acc[p][nt] = __builtin_amdgcn_mfma_f32_16x16x32_bf16(
                        Am, Bf[nt], acc[p][nt], 0, 0, 0);
                    acc[p][nt] = __builtin_amdgcn_mfma_f32_16x16x32_bf16(
                        Al, Bf[nt], acc[p][nt], 0, 0, 0);
                }
            }
        }
    }

#pragma unroll
    for (int bl = 0; bl < 2; ++bl) {
        __syncthreads();
#pragma unroll
        for (int p = 0; p < 2; ++p)
#pragma unroll
            for (int th = 0; th < 2; ++th) {
                int t = th * 16 + lm;
                if (t < TT) {
                    int ob = w * 32 + p * 16 + quad * 4;
#pragma unroll
                    for (int v = 0; v < 4; ++v)
                        ys[(ob + v) * 27 + t] = acc[p][bl * 2 + th][v];
                }
            }
        __syncthreads();
        if (tid < 256) {
            const int o = tid;
            float scale = gamma[o] / sqrtf(var[o] + 1e-5f);
            float ofs   = (bias[o] - mean[o]) * scale + beta[o];
            unsigned short* dst =
                (unsigned short*)spk2 + (size_t)(b0 + bl) * (TT * 256) + o;
            const float* yrow = &ys[o * 27];
            float memv = 0.f;
#pragma unroll
            for (int t = 0; t < TT; ++t) {
                float a     = yrow[t] * scale + ofs;
                float reset = (memv > 1.0f) ? 1.0f : 0.f;
                memv        = 0.95f * memv + a - reset;
                dst[t * 256] = (memv > 1.0f) ? 0x3F80 : 0;
            }
        }
    }
}

// ---------------------------------------------------------------------------
// Layer 3 (MFMA, compact/full-occupancy): 512 thr = 8 waves; wave w handles
// (bl = w&1, th = (w>>1)&1, p = (w>>2)&1) -> one 16x16 tile each.
// O padded 20->32; bias + LIF; writes spk3 ++ mem3 (fp32).
// ---------------------------------------------------------------------------
__global__ __launch_bounds__(512, 4)
void conv3_mfma(const __bf16* __restrict__ spk2,
                const __bf16* __restrict__ K3hi,
                const __bf16* __restrict__ K3mid,
                const __bf16* __restrict__ K3lo,
                const float* __restrict__ b3,
                float* __restrict__ out) {
    __shared__ __align__(16) char smem[27456];   // xs [2][26][264] bf16
    __bf16* xs = (__bf16*)smem;
    __shared__ float ys[2 * 32 * 27];

    const int b0   = blockIdx.x * 2;
    const int tid  = threadIdx.x;
    const int w    = tid >> 6;
    const int lane = tid & 63;
    const int lm   = lane & 15;
    const int quad = lane >> 4;

    {
        uint32_t* xz = (uint32_t*)smem;
        for (int k = tid; k < XSZ2; k += 512) xz[k] = 0u;
    }
    __syncthreads();
#pragma unroll
    for (int bl = 0; bl < 2; ++bl) {
        const __bf16* src = spk2 + (size_t)(b0 + bl) * (TT * 256);
        for (int k = tid; k < TT * 256; k += 512) {
            int t = k >> 8, i = k & 255;
            xs[bl * XSZ2 + t * XC + i] = src[k];
        }
    }
    __syncthreads();

    const int bl = w & 1;
    const int th = (w >> 1) & 1;
    const int p  = (w >> 2) & 1;

    f32x4 acc = (f32x4){0.f, 0.f, 0.f, 0.f};

    for (int j = 0; j < MAXD; ++j) {
        int r = th * 16 + lm + j - 10;
        r = ((unsigned)r < 25u) ? r : 25;
        for (int ic = 0; ic < 8; ++ic) {
            const int col = ic * 32 + quad * 8;
            bf16x8 Bf = *(const bf16x8*)&xs[bl * XSZ2 + r * XC + col];
            const size_t kofs = ((size_t)(j * 32 + p * 16 + lm)) * 256 + col;
            bf16x8 Ah = *(const bf16x8*)(K3hi + kofs);
            bf16x8 Am = *(const bf16x8*)(K3mid + kofs);
            bf16x8 Al = *(const bf16x8*)(K3lo + kofs);
            acc = __builtin_amdgcn_mfma_f32_16x16x32_bf16(Ah, Bf, acc, 0, 0, 0);
            acc = __builtin_amdgcn_mfma_f32_16x16x32_bf16(Am, Bf, acc, 0, 0, 0);
            acc = __builtin_amdgcn_mfma_f32_16x16x32_bf16(Al, Bf, acc, 0, 0, 0);
        }
    }

    {
        int t = th * 16 + lm;
        if (t < TT) {
#pragma unroll
            for (int v = 0; v < 4; ++v)
                ys[(bl * 32 + p * 16 + quad * 4 + v) * 27 + t] = acc[v];
        }
    }
    __syncthreads();

    if (tid < 40) {
        const int bl2 = tid / 20;
        const int o   = tid % 20;
        float memv = 0.f;
        float bo   = b3[o];
        const float* yrow = &ys[(bl2 * 32 + o) * 27];
#pragma unroll
        for (int t = 0; t < TT; ++t) {
            float a     = yrow[t] + bo;
            float reset = (memv > 1.0f) ? 1.0f : 0.f;
            memv        = 0.95f * memv + a - reset;
            float spk   = (memv > 1.0f) ? 1.0f : 0.f;
            out[(t * BB + (b0 + bl2)) * 20 + o]          = spk;
            out[TT * BB * 20 + (t * BB + (b0 + bl2)) * 20 + o] = memv;
        }
    }
}

// ---------------------------------------------------------------------------
extern "C" void kernel_launch(void* const* d_in, const int* in_sizes, int n_in,
                              void* d_out, int out_size, void* d_ws, size_t ws_size,
                              hipStream_t stream) {
    const float* data = (const float*)d_in[0];
    const float* W1   = (const float*)d_in[1];
    const float* b1   = (const float*)d_in[2];
    const float* P1   = (const float*)d_in[3];
    const float* SIG1 = (const float*)d_in[4];
    const float* g1   = (const float*)d_in[5];
    const float* be1  = (const float*)d_in[6];
    const float* m1   = (const float*)d_in[7];
    const float* v1   = (const float*)d_in[8];
    const float* W2   = (const float*)d_in[9];
    const float* b2   = (const float*)d_in[10];
    const float* P2   = (const float*)d_in[11];
    const float* SIG2 = (const float*)d_in[12];
    const float* g2   = (const float*)d_in[13];
    const float* be2  = (const float*)d_in[14];
    const float* m2   = (const float*)d_in[15];
    const float* v2   = (const float*)d_in[16];
    const float* W3   = (const float*)d_in[17];
    const float* b3   = (const float*)d_in[18];
    const float* P3   = (const float*)d_in[19];
    const float* SIG3 = (const float*)d_in[20];
    float* out = (float*)d_out;

    // workspace layout (byte offsets, all 16B-aligned)
    char* p = (char*)d_ws;
    __bf16* K1hi  = (__bf16*)p;  p += 901120;    // 11*256*160 bf16
    __bf16* K1mid = (__bf16*)p;  p += 901120;
    __bf16* K1lo  = (__bf16*)p;  p += 901120;
    __bf16* spk1  = (__bf16*)p;  p += 13107200;  // 1024*25*256 bf16
    __bf16* spk2  = (__bf16*)p;  p += 13107200;
    __bf16* K2hi  = (__bf16*)p;  p += 1441792;   // 11*256*256 bf16
    __bf16* K2mid = (__bf16*)p;  p += 1441792;
    __bf16* K2lo  = (__bf16*)p;  p += 1441792;
    __bf16* K3hi  = (__bf16*)p;  p += 180224;    // 11*32*256 bf16
    __bf16* K3mid = (__bf16*)p;  p += 180224;
    __bf16* K3lo  = (__bf16*)p;

    gen_trip<<<(256 * 160 + 255) / 256, 256, 0, stream>>>(
        W1, P1, SIG1, K1hi, K1mid, K1lo, 256, 256, 140, 160);
    gen_trip<<<(256 * 256 + 255) / 256, 256, 0, stream>>>(
        W2, P2, SIG2, K2hi, K2mid, K2lo, 256, 256, 256, 256);
    gen_trip<<<(32 * 256 + 255) / 256, 256, 0, stream>>>(
        W3, P3, SIG3, K3hi, K3mid, K3lo, 20, 32, 256, 256);

    conv1_mfma<<<BB / 2, 512, 0, stream>>>(data, K1hi, K1mid, K1lo,
                                           b1, g1, be1, m1, v1, spk1);
    conv2_mfma<<<BB / 2, 512, 0, stream>>>(spk1, K2hi, K2mid, K2lo,
                                           b2, g2, be2, m2, v2, spk2);
    conv3_mfma<<<BB / 2, 512, 0, stream>>>(spk2, K3hi, K3mid, K3lo, b3, out);
}